// Round 6
// baseline (194.575 us; speedup 1.0000x reference)
//
#include <hip/hip_runtime.h>
#include <cmath>

// ---------------------------------------------------------------------------
// T5 MHSA: x->(QKV proj, f16 MFMA GEMM) -> flash attn w/ T5 bias -> out proj
// All matmuls on MFMA. fp16 intermediates, fp32 accum.
// ---------------------------------------------------------------------------

typedef _Float16 f16x8 __attribute__((ext_vector_type(8)));
typedef _Float16 f16x4 __attribute__((ext_vector_type(4)));
typedef float    f32x4 __attribute__((ext_vector_type(4)));

#define NEG_INF (-__builtin_inff())
#define LOG2E 1.4426950408889634f

#if __has_builtin(__builtin_amdgcn_exp2f)
#define EXP2(x) __builtin_amdgcn_exp2f(x)
#else
#define EXP2(x) exp2f(x)
#endif

__device__ __forceinline__ void gl_lds16(const void* g, void* l) {
  __builtin_amdgcn_global_load_lds(
      (__attribute__((address_space(1))) void*)g,
      (__attribute__((address_space(3))) void*)l,
      16, 0, 0);
}

__device__ __forceinline__ f32x4 mfma32(f16x8 a, f16x8 b, f32x4 c) {
  return __builtin_amdgcn_mfma_f32_16x16x32_f16(a, b, c, 0, 0, 0);
}
__device__ __forceinline__ f32x4 mfma16(f16x4 a, f16x4 b, f32x4 c) {
  return __builtin_amdgcn_mfma_f32_16x16x16f16(a, b, c, 0, 0, 0);
}

// -------------------------------- convert ---------------------------------
__global__ void cvt_kernel(const float* __restrict__ in,
                           _Float16* __restrict__ out, int n4) {
  int i = blockIdx.x * blockDim.x + threadIdx.x;
  if (i >= n4) return;
  float4 v = reinterpret_cast<const float4*>(in)[i];
  f16x4 o;
  o[0] = (_Float16)v.x; o[1] = (_Float16)v.y;
  o[2] = (_Float16)v.z; o[3] = (_Float16)v.w;
  reinterpret_cast<f16x4*>(out)[i] = o;
}

// --------------------------------- GEMM -----------------------------------
// C = A(MxK) * Bm(NxK)^T.  128x128 tile, BK=32, 4 waves (2x2 of 64x64).
// 2-phase pipeline (T3 minimum recipe): stage K-step t+1 into LDS buffer
// cur^1 BEFORE computing K-step t from buffer cur; ONE barrier per step
// (its implicit vmcnt(0) drain lands after ~a full compute phase).
template <int MODE>
__global__ __launch_bounds__(256, 2) void gemm_kernel(
    const _Float16* __restrict__ A, const _Float16* __restrict__ Bm,
    int M, int N, int K,
    const float* __restrict__ bias_q, const float* __restrict__ bias_v,
    _Float16* __restrict__ qkbuf, _Float16* __restrict__ vtbuf,
    const float* __restrict__ bias_o, float* __restrict__ outf) {
  __shared__ __align__(16) _Float16 lds_a[2][128 * 32];
  __shared__ __align__(16) _Float16 lds_b[2][128 * 32];
  const int t = threadIdx.x;
  const int w = t >> 6;
  const int lane = t & 63;
  const int lq = lane & 15, lg = lane >> 4;
  const int wr = w >> 1, wc = w & 1;
  const int m0 = blockIdx.y * 128, n0 = blockIdx.x * 128;

  // staging: thread t -> row t>>2 of tile, 8-elem k-chunk t&3; LDS dest is
  // wave-uniform base (+HW lane*16B) -> linear [128][32] layout
  const _Float16* pA0 = A + (size_t)(m0 + (t >> 2)) * K + (t & 3) * 8;
  const _Float16* pA1 = pA0 + (size_t)64 * K;
  const _Float16* pB0 = Bm + (size_t)(n0 + (t >> 2)) * K + (t & 3) * 8;
  const _Float16* pB1 = pB0 + (size_t)64 * K;
  const int wofs = w * 512;  // wave w's 64 lanes x 8 f16

  f32x4 acc[4][4];
#pragma unroll
  for (int mi = 0; mi < 4; ++mi)
#pragma unroll
    for (int ni = 0; ni < 4; ++ni) acc[mi][ni] = (f32x4){0.f, 0.f, 0.f, 0.f};

  // prologue: stage K-step 0 into buffer 0
  gl_lds16(pA0, &lds_a[0][wofs]);
  gl_lds16(pA1, &lds_a[0][2048 + wofs]);
  gl_lds16(pB0, &lds_b[0][wofs]);
  gl_lds16(pB1, &lds_b[0][2048 + wofs]);
  __syncthreads();  // implicit vmcnt(0) drain

  int cur = 0;
  for (int k0 = 0; k0 < K; k0 += 32) {
    const int nx = cur ^ 1;
    if (k0 + 32 < K) {  // prefetch next K-step into the other buffer
      gl_lds16(pA0 + k0 + 32, &lds_a[nx][wofs]);
      gl_lds16(pA1 + k0 + 32, &lds_a[nx][2048 + wofs]);
      gl_lds16(pB0 + k0 + 32, &lds_b[nx][wofs]);
      gl_lds16(pB1 + k0 + 32, &lds_b[nx][2048 + wofs]);
    }
    f16x8 af[4], bfr[4];
#pragma unroll
    for (int mi = 0; mi < 4; ++mi)
      af[mi] =
          *(const f16x8*)&lds_a[cur][(wr * 64 + mi * 16 + lq) * 32 + lg * 8];
#pragma unroll
    for (int ni = 0; ni < 4; ++ni)
      bfr[ni] =
          *(const f16x8*)&lds_b[cur][(wc * 64 + ni * 16 + lq) * 32 + lg * 8];
    __builtin_amdgcn_s_setprio(1);
#pragma unroll
    for (int mi = 0; mi < 4; ++mi)
#pragma unroll
      for (int ni = 0; ni < 4; ++ni)
        acc[mi][ni] = mfma32(af[mi], bfr[ni], acc[mi][ni]);
    __builtin_amdgcn_s_setprio(0);
    __syncthreads();  // waits staged loads (issued ~a compute phase ago)
    cur = nx;
  }

  if (MODE == 0) {
    const bool isqk = (n0 < 2048);
#pragma unroll
    for (int mi = 0; mi < 4; ++mi)
#pragma unroll
      for (int ni = 0; ni < 4; ++ni)
#pragma unroll
        for (int r = 0; r < 4; ++r) {
          const int mg = m0 + wr * 64 + mi * 16 + lg * 4 + r;
          const int ng = n0 + wc * 64 + ni * 16 + lq;
          const int bb = mg >> 10, ii = mg & 1023;
          float val = acc[mi][ni][r];
          if (isqk) {
            val += bias_q[ng];
            const int hh = ng >> 7, cc = ng & 127;
            qkbuf[((size_t)((bb * 16 + hh) * 1024 + ii)) * 128 + cc] =
                (_Float16)val;
          } else {
            const int nn = ng - 2048;
            val += bias_v[nn];
            const int hh = nn >> 6, dv = nn & 63;
            vtbuf[((size_t)((bb * 16 + hh) * 64 + dv)) * 1024 + ii] =
                (_Float16)val;
          }
        }
  } else {
#pragma unroll
    for (int mi = 0; mi < 4; ++mi)
#pragma unroll
      for (int ni = 0; ni < 4; ++ni)
#pragma unroll
        for (int r = 0; r < 4; ++r) {
          const int mg = m0 + wr * 64 + mi * 16 + lg * 4 + r;
          const int ng = n0 + wc * 64 + ni * 16 + lq;
          outf[(size_t)mg * N + ng] = acc[mi][ni][r] + bias_o[ng];
        }
  }
}

// ------------------------------- attention --------------------------------
// Block = 4 waves, owns q-tile PAIR (tA=b4, tB=15-b4) of one (b,h): constant
// work per block (17 tile-units), all waves share the same j-range ->
// barrier-synced LDS staging of K/V tiles (KVBLK=64), double-buffered,
// coalesced global_load_lds with pre-swizzled source (XOR chunk swizzle) so
// swizzled LDS reads are bank-conflict-free.
// S^T = mfma_16x16x32(K,Q): lane holds S[q=lq][j=js*16+lg*4+r], which IS the
// A-fragment of mfma_16x16x16 -> PV without repack.
// Softmax: defer-max on per-lane max (common path: zero cross-lane ops).
__device__ __forceinline__ void stage_kv(const _Float16* __restrict__ kb,
                                         const _Float16* __restrict__ vtb,
                                         int j0, _Float16* kl, _Float16* vl,
                                         int t) {
  const int r0 = t >> 3, c0 = t & 7;
  const int r1 = r0 + 32;
  const int kc0 = c0 ^ (r0 & 7), kc1 = c0 ^ (r1 & 7);
  // K tile rows j (64 x 64 f16); source row stride 128 (q|k interleaved)
  gl_lds16(kb + (size_t)(j0 + r0) * 128 + kc0 * 8, kl + t * 8);
  gl_lds16(kb + (size_t)(j0 + r1) * 128 + kc1 * 8, kl + (t + 256) * 8);
  // V^T tile rows d (64 x 64 f16); source row stride 1024
  gl_lds16(vtb + (size_t)r0 * 1024 + j0 + kc0 * 8, vl + t * 8);
  gl_lds16(vtb + (size_t)r1 * 1024 + j0 + kc1 * 8, vl + (t + 256) * 8);
}

__device__ __forceinline__ void softmax16(f32x4 (&st)[4], f16x4 (&ph)[4],
                                          int qi, int j0, bool far,
                                          const float* __restrict__ tab,
                                          float t128, int lg4, float& m_run,
                                          float& l_part, f32x4 (&oacc)[4]) {
  float xs[16];
  float lmax = NEG_INF;
  if (far) {  // all dd > 128: bias = tab[128], no mask possible
#pragma unroll
    for (int js = 0; js < 4; ++js)
#pragma unroll
      for (int r = 0; r < 4; ++r) {
        const float xv = fmaf(st[js][r], 0.125f * LOG2E, t128);
        xs[js * 4 + r] = xv;
        lmax = fmaxf(lmax, xv);
      }
  } else {
#pragma unroll
    for (int js = 0; js < 4; ++js)
#pragma unroll
      for (int r = 0; r < 4; ++r) {
        const int jj = j0 + js * 16 + lg4 + r;
        const int dd = qi - jj;
        const int idx = dd < 0 ? 0 : (dd > 128 ? 128 : dd);
        const float xv =
            (dd < 0) ? NEG_INF : fmaf(st[js][r], 0.125f * LOG2E, tab[idx]);
        xs[js * 4 + r] = xv;
        lmax = fmaxf(lmax, xv);
      }
  }
  // defer-max: invariant xs <= m_run + 8 after this block -> p <= 2^8
  if (__any(lmax > m_run + 8.0f)) {
    float tmax = fmaxf(lmax, __shfl_xor(lmax, 16));
    tmax = fmaxf(tmax, __shfl_xor(tmax, 32));
    const float m_new = fmaxf(m_run, tmax);
    const float sf = EXP2(m_run - m_new);
    m_run = m_new;
    l_part *= sf;
    f32x4 sfv;
#pragma unroll
    for (int r = 0; r < 4; ++r) sfv[r] = __shfl(sf, lg4 + r);
#pragma unroll
    for (int db = 0; db < 4; ++db) oacc[db] *= sfv;
  }
  float ls = 0.f;
#pragma unroll
  for (int js = 0; js < 4; ++js)
#pragma unroll
    for (int r = 0; r < 4; ++r) {
      const float p = EXP2(xs[js * 4 + r] - m_run);
      ls += p;
      ph[js][r] = (_Float16)p;
    }
  l_part += ls;
}

__global__ __launch_bounds__(256, 4) void attn_kernel(
    const _Float16* __restrict__ qk,  // [B*H][1024][128] (q | k)
    const _Float16* __restrict__ vt,  // [B*H][64][1024]  (V^T)
    const float* __restrict__ bias,   // [32][16]
    _Float16* __restrict__ ao) {      // [B][1024][H*64]
  __shared__ __align__(16) _Float16 kls[2][64 * 64];
  __shared__ __align__(16) _Float16 vls[2][64 * 64];
  __shared__ float tab[132];
  const int t = threadIdx.x;
  const int bid = blockIdx.x;
  // XCD swizzle: XCD x serves bh [x*16, x*16+16) -> K/V working set ~4MB/L2
  const int bh = (bid & 7) * 16 + (bid >> 6);
  const int b4 = (bid >> 3) & 7;
  const int h = bh & 15, b = bh >> 4;
  if (t < 129) {
    const int bucket =
        (t <= 16) ? t : 16 + (int)(log((double)(t - 15)) * 15.0 / log(113.0));
    tab[t] = bias[bucket * 16 + h] * LOG2E;
  }

  const int w = t >> 6, lane = t & 63;
  const int lq = lane & 15, lg = lane >> 4;
  const int lg4 = lg * 4, lg8 = lg * 8;
  const int tA = b4, tB = 15 - b4;  // q-tile pair: tA+1 + tB+1 = 17 units
  const int q0A = tA * 64 + w * 16, q0B = tB * 64 + w * 16;
  const int qA = q0A + lq, qB = q0B + lq;
  const _Float16* qkb = qk + (size_t)bh * 1024 * 128;
  const _Float16* kb = qkb + 64;
  const _Float16* vtb = vt + (size_t)bh * 64 * 1024;

  const f16x8 qfA0 = *(const f16x8*)&qkb[qA * 128 + lg8];
  const f16x8 qfA1 = *(const f16x8*)&qkb[qA * 128 + 32 + lg8];
  const f16x8 qfB0 = *(const f16x8*)&qkb[qB * 128 + lg8];
  const f16x8 qfB1 = *(const f16x8*)&qkb[qB * 128 + 32 + lg8];

  f32x4 oA[4], oB[4];
#pragma unroll
  for (int db = 0; db < 4; ++db) {
    oA[db] = (f32x4){0.f, 0.f, 0.f, 0.f};
    oB[db] = (f32x4){0.f, 0.f, 0.f, 0.f};
  }
  float mA = NEG_INF, lAp = 0.f, mB = NEG_INF, lBp = 0.f;

  stage_kv(kb, vtb, 0, kls[0], vls[0], t);
  __syncthreads();
  const float t128 = tab[128];
  const int krsw = lq & 7;
  const int vsw = (lq & 7) << 1;
  int cur = 0;

  for (int jt = 0; jt <= tB; ++jt) {
    const int j0 = jt * 64;
    if (jt < tB) stage_kv(kb, vtb, j0 + 64, kls[cur ^ 1], vls[cur ^ 1], t);
    const bool aact = (jt <= tA);
    const _Float16* kbf = kls[cur];
    const _Float16* vbf = vls[cur];

    // QK^T for both q-sets from shared K frags (swizzled LDS reads)
    f32x4 stA[4], stB[4];
#pragma unroll
    for (int js = 0; js < 4; ++js) {
      const int rowb = (js * 16 + lq) * 64;
      const f16x8 kf0 = *(const f16x8*)&kbf[rowb + ((lg ^ krsw) << 3)];
      const f16x8 kf1 = *(const f16x8*)&kbf[rowb + (((lg + 4) ^ krsw) << 3)];
      if (aact) {
        stA[js] = mfma32(kf0, qfA0, (f32x4){0.f, 0.f, 0.f, 0.f});
        stA[js] = mfma32(kf1, qfA1, stA[js]);
      }
      stB[js] = mfma32(kf0, qfB0, (f32x4){0.f, 0.f, 0.f, 0.f});
      stB[js] = mfma32(kf1, qfB1, stB[js]);
    }

    f16x4 phA[4], phB[4];
    if (aact)
      softmax16(stA, phA, qA, j0, q0A - j0 >= 192, tab, t128, lg4, mA, lAp,
                oA);
    softmax16(stB, phB, qB, j0, q0B - j0 >= 192, tab, t128, lg4, mB, lBp, oB);

    // PV from shared V frags (swizzled LDS reads)
#pragma unroll
    for (int js = 0; js < 4; ++js)
#pragma unroll
      for (int db = 0; db < 4; ++db) {
        const f16x4 vf = *(const f16x4*)&vbf[(db * 16 + lq) * 64 +
                                             ((((js << 2) + lg) ^ vsw) << 2)];
        if (aact) oA[db] = mfma16(phA[js], vf, oA[db]);
        oB[db] = mfma16(phB[js], vf, oB[db]);
      }

    __syncthreads();
    cur ^= 1;
  }

  _Float16* aob = ao + ((size_t)b * 1024) * 1024 + h * 64;
  {
    float lt = lAp + __shfl_xor(lAp, 16);
    lt += __shfl_xor(lt, 32);
    f32x4 linv;
#pragma unroll
    for (int r = 0; r < 4; ++r) linv[r] = 1.0f / __shfl(lt, lg4 + r);
#pragma unroll
    for (int db = 0; db < 4; ++db)
#pragma unroll
      for (int r = 0; r < 4; ++r)
        aob[(size_t)(q0A + lg4 + r) * 1024 + db * 16 + lq] =
            (_Float16)(oA[db][r] * linv[r]);
  }
  {
    float lt = lBp + __shfl_xor(lBp, 16);
    lt += __shfl_xor(lt, 32);
    f32x4 linv;
#pragma unroll
    for (int r = 0; r < 4; ++r) linv[r] = 1.0f / __shfl(lt, lg4 + r);
#pragma unroll
    for (int db = 0; db < 4; ++db)
#pragma unroll
      for (int r = 0; r < 4; ++r)
        aob[(size_t)(q0B + lg4 + r) * 1024 + db * 16 + lq] =
            (_Float16)(oB[db][r] * linv[r]);
  }
}

// -------------------------------- launch ----------------------------------
extern "C" void kernel_launch(void* const* d_in, const int* in_sizes, int n_in,
                              void* d_out, int out_size, void* d_ws,
                              size_t ws_size, hipStream_t stream) {
  const float* x = (const float*)d_in[0];
  const float* qk_w = (const float*)d_in[1];
  const float* qk_b = (const float*)d_in[2];
  const float* v_w = (const float*)d_in[3];
  const float* v_b = (const float*)d_in[4];
  const float* out_w = (const float*)d_in[5];
  const float* out_b = (const float*)d_in[6];
  const float* bias = (const float*)d_in[7];
  float* out = (float*)d_out;

  // workspace (fp16 elems): xb 8M | wb 3M | owb 1M | qk 16M | vt 8M | ao 8M
  _Float16* xb = (_Float16*)d_ws;
  _Float16* wb = xb + (size_t)8388608;
  _Float16* owb = wb + (size_t)3145728;
  _Float16* qkbuf = owb + (size_t)1048576;
  _Float16* vtbuf = qkbuf + (size_t)16777216;
  _Float16* ao = vtbuf + (size_t)8388608;

  cvt_kernel<<<8192, 256, 0, stream>>>(x, xb, 2097152);
  cvt_kernel<<<2048, 256, 0, stream>>>(qk_w, wb, 524288);
  cvt_kernel<<<1024, 256, 0, stream>>>(v_w, wb + 2097152, 262144);
  cvt_kernel<<<1024, 256, 0, stream>>>(out_w, owb, 262144);

  // fused QKV projection: M=8192, N=3072 (2048 qk | 1024 v), K=1024
  gemm_kernel<0><<<dim3(24, 64), 256, 0, stream>>>(
      xb, wb, 8192, 3072, 1024, qk_b, v_b, qkbuf, vtbuf, nullptr, nullptr);

  // flash attention: 8 balanced blocks per (b,h)
  attn_kernel<<<1024, 256, 0, stream>>>(qkbuf, vtbuf, bias, ao);

  // output projection: M=8192, N=1024, K=1024 -> fp32 d_out
  gemm_kernel<1><<<dim3(8, 64), 256, 0, stream>>>(
      ao, owb, 8192, 1024, 1024, nullptr, nullptr, nullptr, nullptr, out_b, out);
}

// Round 7
// 194.195 us; speedup vs baseline: 1.0020x; 1.0020x over previous
//
#include <hip/hip_runtime.h>
#include <cmath>

// ---------------------------------------------------------------------------
// T5 MHSA: x->(QKV proj, f16 MFMA GEMM) -> flash attn w/ T5 bias -> out proj
// All matmuls on MFMA. fp16 intermediates, fp32 accum.
// ---------------------------------------------------------------------------

typedef _Float16 f16x8 __attribute__((ext_vector_type(8)));
typedef _Float16 f16x4 __attribute__((ext_vector_type(4)));
typedef float    f32x4 __attribute__((ext_vector_type(4)));

#define NEG_INF (-__builtin_inff())
#define LOG2E 1.4426950408889634f

#if __has_builtin(__builtin_amdgcn_exp2f)
#define EXP2(x) __builtin_amdgcn_exp2f(x)
#else
#define EXP2(x) exp2f(x)
#endif

__device__ __forceinline__ void gl_lds16(const void* g, void* l) {
  __builtin_amdgcn_global_load_lds(
      (__attribute__((address_space(1))) void*)g,
      (__attribute__((address_space(3))) void*)l,
      16, 0, 0);
}

__device__ __forceinline__ f32x4 mfma32(f16x8 a, f16x8 b, f32x4 c) {
  return __builtin_amdgcn_mfma_f32_16x16x32_f16(a, b, c, 0, 0, 0);
}
__device__ __forceinline__ f32x4 mfma16(f16x4 a, f16x4 b, f32x4 c) {
  return __builtin_amdgcn_mfma_f32_16x16x16f16(a, b, c, 0, 0, 0);
}

// -------------------------------- convert ---------------------------------
__global__ void cvt_kernel(const float* __restrict__ in,
                           _Float16* __restrict__ out, int n4) {
  int i = blockIdx.x * blockDim.x + threadIdx.x;
  if (i >= n4) return;
  float4 v = reinterpret_cast<const float4*>(in)[i];
  f16x4 o;
  o[0] = (_Float16)v.x; o[1] = (_Float16)v.y;
  o[2] = (_Float16)v.z; o[3] = (_Float16)v.w;
  reinterpret_cast<f16x4*>(out)[i] = o;
}

// --------------------------------- GEMM -----------------------------------
// C = A(MxK) * Bm(NxK)^T.  128x128 tile, BK=32, 4 waves (2x2 of 64x64).
// 2-phase pipeline with COUNTED vmcnt (T3+T4): raw s_barrier, never drain
// vmcnt to 0 in the main loop -> next tile's 4 global_load_lds stay in
// flight across the barrier and hide a full iteration of latency.
template <int MODE>
__global__ __launch_bounds__(256, 4) void gemm_kernel(
    const _Float16* __restrict__ A, const _Float16* __restrict__ Bm,
    int M, int N, int K,
    const float* __restrict__ bias_q, const float* __restrict__ bias_v,
    _Float16* __restrict__ qkbuf, _Float16* __restrict__ vtbuf,
    const float* __restrict__ bias_o, float* __restrict__ outf) {
  __shared__ __align__(16) _Float16 lds_a[2][128 * 32];
  __shared__ __align__(16) _Float16 lds_b[2][128 * 32];
  const int t = threadIdx.x;
  const int w = t >> 6;
  const int lane = t & 63;
  const int lq = lane & 15, lg = lane >> 4;
  const int wr = w >> 1, wc = w & 1;
  const int m0 = blockIdx.y * 128, n0 = blockIdx.x * 128;

  // staging: thread t -> row t>>2 of tile, 8-elem k-chunk t&3; LDS dest is
  // wave-uniform base (+HW lane*16B) -> linear [128][32] layout
  const _Float16* pA0 = A + (size_t)(m0 + (t >> 2)) * K + (t & 3) * 8;
  const _Float16* pA1 = pA0 + (size_t)64 * K;
  const _Float16* pB0 = Bm + (size_t)(n0 + (t >> 2)) * K + (t & 3) * 8;
  const _Float16* pB1 = pB0 + (size_t)64 * K;
  const int wofs = w * 512;  // wave w's 64 lanes x 8 f16

#define GEMM_STAGE(buf, kk)                      \
  do {                                           \
    gl_lds16(pA0 + (kk), &lds_a[buf][wofs]);     \
    gl_lds16(pA1 + (kk), &lds_a[buf][2048 + wofs]); \
    gl_lds16(pB0 + (kk), &lds_b[buf][wofs]);     \
    gl_lds16(pB1 + (kk), &lds_b[buf][2048 + wofs]); \
  } while (0)

#define GEMM_COMPUTE(buf)                                                    \
  do {                                                                       \
    f16x8 af[4], bfr[4];                                                     \
    _Pragma("unroll") for (int mi = 0; mi < 4; ++mi) af[mi] =                \
        *(const f16x8*)&lds_a[buf][(wr * 64 + mi * 16 + lq) * 32 + lg * 8];  \
    _Pragma("unroll") for (int ni = 0; ni < 4; ++ni) bfr[ni] =               \
        *(const f16x8*)&lds_b[buf][(wc * 64 + ni * 16 + lq) * 32 + lg * 8];  \
    __builtin_amdgcn_s_setprio(1);                                           \
    _Pragma("unroll") for (int mi = 0; mi < 4; ++mi)                         \
        _Pragma("unroll") for (int ni = 0; ni < 4; ++ni) acc[mi][ni] =       \
            mfma32(af[mi], bfr[ni], acc[mi][ni]);                            \
    __builtin_amdgcn_s_setprio(0);                                           \
  } while (0)

  f32x4 acc[4][4];
#pragma unroll
  for (int mi = 0; mi < 4; ++mi)
#pragma unroll
    for (int ni = 0; ni < 4; ++ni) acc[mi][ni] = (f32x4){0.f, 0.f, 0.f, 0.f};

  // prologue: stage K-step 0 into buffer 0
  GEMM_STAGE(0, 0);

  int cur = 0;
  for (int k0 = 0; k0 < K - 32; k0 += 32) {
    const int nx = cur ^ 1;
    GEMM_STAGE(nx, k0 + 32);  // outstanding: 4 (tile t) + 4 (tile t+1)
    asm volatile("s_waitcnt vmcnt(4)" ::: "memory");  // tile t landed
    __builtin_amdgcn_s_barrier();                     // ...in all waves
    asm volatile("" ::: "memory");
    GEMM_COMPUTE(cur);
    asm volatile("" ::: "memory");
    __builtin_amdgcn_s_barrier();  // all waves done reading buf[cur]
    cur = nx;
  }
  // last tile: drain remaining 4 loads
  asm volatile("s_waitcnt vmcnt(0)" ::: "memory");
  __builtin_amdgcn_s_barrier();
  asm volatile("" ::: "memory");
  GEMM_COMPUTE(cur);
#undef GEMM_STAGE
#undef GEMM_COMPUTE

  if (MODE == 0) {
    const bool isqk = (n0 < 2048);
#pragma unroll
    for (int mi = 0; mi < 4; ++mi)
#pragma unroll
      for (int ni = 0; ni < 4; ++ni)
#pragma unroll
        for (int r = 0; r < 4; ++r) {
          const int mg = m0 + wr * 64 + mi * 16 + lg * 4 + r;
          const int ng = n0 + wc * 64 + ni * 16 + lq;
          const int bb = mg >> 10, ii = mg & 1023;
          float val = acc[mi][ni][r];
          if (isqk) {
            val += bias_q[ng];
            const int hh = ng >> 7, cc = ng & 127;
            qkbuf[((size_t)((bb * 16 + hh) * 1024 + ii)) * 128 + cc] =
                (_Float16)val;
          } else {
            const int nn = ng - 2048;
            val += bias_v[nn];
            const int hh = nn >> 6, dv = nn & 63;
            vtbuf[((size_t)((bb * 16 + hh) * 64 + dv)) * 1024 + ii] =
                (_Float16)val;
          }
        }
  } else {
#pragma unroll
    for (int mi = 0; mi < 4; ++mi)
#pragma unroll
      for (int ni = 0; ni < 4; ++ni)
#pragma unroll
        for (int r = 0; r < 4; ++r) {
          const int mg = m0 + wr * 64 + mi * 16 + lg * 4 + r;
          const int ng = n0 + wc * 64 + ni * 16 + lq;
          outf[(size_t)mg * N + ng] = acc[mi][ni][r] + bias_o[ng];
        }
  }
}

// ------------------------------- attention --------------------------------
// Block = 4 waves, owns q-tile PAIR (tA=b4, tB=15-b4) of one (b,h): constant
// work per block (17 tile-units), all waves share the same j-range ->
// barrier-synced LDS staging of K/V tiles (KVBLK=64), double-buffered,
// coalesced global_load_lds with pre-swizzled source (XOR chunk swizzle) so
// swizzled LDS reads are bank-conflict-free.
// S^T = mfma_16x16x32(K,Q): lane holds S[q=lq][j=js*16+lg*4+r], which IS the
// A-fragment of mfma_16x16x16 -> PV without repack.
// Softmax: defer-max on per-lane max (common path: zero cross-lane ops).
__device__ __forceinline__ void stage_kv(const _Float16* __restrict__ kb,
                                         const _Float16* __restrict__ vtb,
                                         int j0, _Float16* kl, _Float16* vl,
                                         int t) {
  const int r0 = t >> 3, c0 = t & 7;
  const int r1 = r0 + 32;
  const int kc0 = c0 ^ (r0 & 7), kc1 = c0 ^ (r1 & 7);
  // K tile rows j (64 x 64 f16); source row stride 128 (q|k interleaved)
  gl_lds16(kb + (size_t)(j0 + r0) * 128 + kc0 * 8, kl + t * 8);
  gl_lds16(kb + (size_t)(j0 + r1) * 128 + kc1 * 8, kl + (t + 256) * 8);
  // V^T tile rows d (64 x 64 f16); source row stride 1024
  gl_lds16(vtb + (size_t)r0 * 1024 + j0 + kc0 * 8, vl + t * 8);
  gl_lds16(vtb + (size_t)r1 * 1024 + j0 + kc1 * 8, vl + (t + 256) * 8);
}

__device__ __forceinline__ void softmax16(f32x4 (&st)[4], f16x4 (&ph)[4],
                                          int qi, int j0, bool far,
                                          const float* __restrict__ tab,
                                          float t128, int lg4, float& m_run,
                                          float& l_part, f32x4 (&oacc)[4]) {
  float xs[16];
  float lmax = NEG_INF;
  if (far) {  // all dd > 128: bias = tab[128], no mask possible
#pragma unroll
    for (int js = 0; js < 4; ++js)
#pragma unroll
      for (int r = 0; r < 4; ++r) {
        const float xv = fmaf(st[js][r], 0.125f * LOG2E, t128);
        xs[js * 4 + r] = xv;
        lmax = fmaxf(lmax, xv);
      }
  } else {
#pragma unroll
    for (int js = 0; js < 4; ++js)
#pragma unroll
      for (int r = 0; r < 4; ++r) {
        const int jj = j0 + js * 16 + lg4 + r;
        const int dd = qi - jj;
        const int idx = dd < 0 ? 0 : (dd > 128 ? 128 : dd);
        const float xv =
            (dd < 0) ? NEG_INF : fmaf(st[js][r], 0.125f * LOG2E, tab[idx]);
        xs[js * 4 + r] = xv;
        lmax = fmaxf(lmax, xv);
      }
  }
  // defer-max: invariant xs <= m_run + 8 after this block -> p <= 2^8
  if (__any(lmax > m_run + 8.0f)) {
    float tmax = fmaxf(lmax, __shfl_xor(lmax, 16));
    tmax = fmaxf(tmax, __shfl_xor(tmax, 32));
    const float m_new = fmaxf(m_run, tmax);
    const float sf = EXP2(m_run - m_new);
    m_run = m_new;
    l_part *= sf;
    f32x4 sfv;
#pragma unroll
    for (int r = 0; r < 4; ++r) sfv[r] = __shfl(sf, lg4 + r);
#pragma unroll
    for (int db = 0; db < 4; ++db) oacc[db] *= sfv;
  }
  float ls = 0.f;
#pragma unroll
  for (int js = 0; js < 4; ++js)
#pragma unroll
    for (int r = 0; r < 4; ++r) {
      const float p = EXP2(xs[js * 4 + r] - m_run);
      ls += p;
      ph[js][r] = (_Float16)p;
    }
  l_part += ls;
}

__global__ __launch_bounds__(256, 4) void attn_kernel(
    const _Float16* __restrict__ qk,  // [B*H][1024][128] (q | k)
    const _Float16* __restrict__ vt,  // [B*H][64][1024]  (V^T)
    const float* __restrict__ bias,   // [32][16]
    _Float16* __restrict__ ao) {      // [B][1024][H*64]
  __shared__ __align__(16) _Float16 kls[2][64 * 64];
  __shared__ __align__(16) _Float16 vls[2][64 * 64];
  __shared__ float tab[132];
  const int t = threadIdx.x;
  const int bid = blockIdx.x;
  // XCD swizzle: XCD x serves bh [x*16, x*16+16) -> K/V working set ~4MB/L2
  const int bh = (bid & 7) * 16 + (bid >> 6);
  const int b4 = (bid >> 3) & 7;
  const int h = bh & 15, b = bh >> 4;
  if (t < 129) {
    const int bucket =
        (t <= 16) ? t : 16 + (int)(log((double)(t - 15)) * 15.0 / log(113.0));
    tab[t] = bias[bucket * 16 + h] * LOG2E;
  }

  const int w = t >> 6, lane = t & 63;
  const int lq = lane & 15, lg = lane >> 4;
  const int lg4 = lg * 4, lg8 = lg * 8;
  const int tA = b4, tB = 15 - b4;  // q-tile pair: tA+1 + tB+1 = 17 units
  const int q0A = tA * 64 + w * 16, q0B = tB * 64 + w * 16;
  const int qA = q0A + lq, qB = q0B + lq;
  const _Float16* qkb = qk + (size_t)bh * 1024 * 128;
  const _Float16* kb = qkb + 64;
  const _Float16* vtb = vt + (size_t)bh * 64 * 1024;

  const f16x8 qfA0 = *(const f16x8*)&qkb[qA * 128 + lg8];
  const f16x8 qfA1 = *(const f16x8*)&qkb[qA * 128 + 32 + lg8];
  const f16x8 qfB0 = *(const f16x8*)&qkb[qB * 128 + lg8];
  const f16x8 qfB1 = *(const f16x8*)&qkb[qB * 128 + 32 + lg8];

  f32x4 oA[4], oB[4];
#pragma unroll
  for (int db = 0; db < 4; ++db) {
    oA[db] = (f32x4){0.f, 0.f, 0.f, 0.f};
    oB[db] = (f32x4){0.f, 0.f, 0.f, 0.f};
  }
  float mA = NEG_INF, lAp = 0.f, mB = NEG_INF, lBp = 0.f;

  stage_kv(kb, vtb, 0, kls[0], vls[0], t);
  __syncthreads();
  const float t128 = tab[128];
  const int krsw = lq & 7;
  const int vsw = (lq & 7) << 1;
  int cur = 0;

  for (int jt = 0; jt <= tB; ++jt) {
    const int j0 = jt * 64;
    if (jt < tB) stage_kv(kb, vtb, j0 + 64, kls[cur ^ 1], vls[cur ^ 1], t);
    const bool aact = (jt <= tA);
    const _Float16* kbf = kls[cur];
    const _Float16* vbf = vls[cur];

    // QK^T for both q-sets from shared K frags (swizzled LDS reads)
    f32x4 stA[4], stB[4];
#pragma unroll
    for (int js = 0; js < 4; ++js) {
      const int rowb = (js * 16 + lq) * 64;
      const f16x8 kf0 = *(const f16x8*)&kbf[rowb + ((lg ^ krsw) << 3)];
      const f16x8 kf1 = *(const f16x8*)&kbf[rowb + (((lg + 4) ^ krsw) << 3)];
      if (aact) {
        stA[js] = mfma32(kf0, qfA0, (f32x4){0.f, 0.f, 0.f, 0.f});
        stA[js] = mfma32(kf1, qfA1, stA[js]);
      }
      stB[js] = mfma32(kf0, qfB0, (f32x4){0.f, 0.f, 0.f, 0.f});
      stB[js] = mfma32(kf1, qfB1, stB[js]);
    }

    f16x4 phA[4], phB[4];
    if (aact)
      softmax16(stA, phA, qA, j0, q0A - j0 >= 192, tab, t128, lg4, mA, lAp,
                oA);
    softmax16(stB, phB, qB, j0, q0B - j0 >= 192, tab, t128, lg4, mB, lBp, oB);

    // PV from shared V frags (swizzled LDS reads)
#pragma unroll
    for (int js = 0; js < 4; ++js)
#pragma unroll
      for (int db = 0; db < 4; ++db) {
        const f16x4 vf = *(const f16x4*)&vbf[(db * 16 + lq) * 64 +
                                             ((((js << 2) + lg) ^ vsw) << 2)];
        if (aact) oA[db] = mfma16(phA[js], vf, oA[db]);
        oB[db] = mfma16(phB[js], vf, oB[db]);
      }

    __syncthreads();
    cur ^= 1;
  }

  _Float16* aob = ao + ((size_t)b * 1024) * 1024 + h * 64;
  {
    float lt = lAp + __shfl_xor(lAp, 16);
    lt += __shfl_xor(lt, 32);
    f32x4 linv;
#pragma unroll
    for (int r = 0; r < 4; ++r) linv[r] = 1.0f / __shfl(lt, lg4 + r);
#pragma unroll
    for (int db = 0; db < 4; ++db)
#pragma unroll
      for (int r = 0; r < 4; ++r)
        aob[(size_t)(q0A + lg4 + r) * 1024 + db * 16 + lq] =
            (_Float16)(oA[db][r] * linv[r]);
  }
  {
    float lt = lBp + __shfl_xor(lBp, 16);
    lt += __shfl_xor(lt, 32);
    f32x4 linv;
#pragma unroll
    for (int r = 0; r < 4; ++r) linv[r] = 1.0f / __shfl(lt, lg4 + r);
#pragma unroll
    for (int db = 0; db < 4; ++db)
#pragma unroll
      for (int r = 0; r < 4; ++r)
        aob[(size_t)(q0B + lg4 + r) * 1024 + db * 16 + lq] =
            (_Float16)(oB[db][r] * linv[r]);
  }
}

// -------------------------------- launch ----------------------------------
extern "C" void kernel_launch(void* const* d_in, const int* in_sizes, int n_in,
                              void* d_out, int out_size, void* d_ws,
                              size_t ws_size, hipStream_t stream) {
  const float* x = (const float*)d_in[0];
  const float* qk_w = (const float*)d_in[1];
  const float* qk_b = (const float*)d_in[2];
  const float* v_w = (const float*)d_in[3];
  const float* v_b = (const float*)d_in[4];
  const float* out_w = (const float*)d_in[5];
  const float* out_b = (const float*)d_in[6];
  const float* bias = (const float*)d_in[7];
  float* out = (float*)d_out;

  // workspace (fp16 elems): xb 8M | wb 3M | owb 1M | qk 16M | vt 8M | ao 8M
  _Float16* xb = (_Float16*)d_ws;
  _Float16* wb = xb + (size_t)8388608;
  _Float16* owb = wb + (size_t)3145728;
  _Float16* qkbuf = owb + (size_t)1048576;
  _Float16* vtbuf = qkbuf + (size_t)16777216;
  _Float16* ao = vtbuf + (size_t)8388608;

  cvt_kernel<<<8192, 256, 0, stream>>>(x, xb, 2097152);
  cvt_kernel<<<2048, 256, 0, stream>>>(qk_w, wb, 524288);
  cvt_kernel<<<1024, 256, 0, stream>>>(v_w, wb + 2097152, 262144);
  cvt_kernel<<<1024, 256, 0, stream>>>(out_w, owb, 262144);

  // fused QKV projection: M=8192, N=3072 (2048 qk | 1024 v), K=1024
  gemm_kernel<0><<<dim3(24, 64), 256, 0, stream>>>(
      xb, wb, 8192, 3072, 1024, qk_b, v_b, qkbuf, vtbuf, nullptr, nullptr);

  // flash attention: 8 balanced blocks per (b,h)
  attn_kernel<<<1024, 256, 0, stream>>>(qkbuf, vtbuf, bias, ao);

  // output projection: M=8192, N=1024, K=1024 -> fp32 d_out
  gemm_kernel<1><<<dim3(8, 64), 256, 0, stream>>>(
      ao, owb, 8192, 1024, 1024, nullptr, nullptr, nullptr, nullptr, out_b, out);
}

// Round 8
// 184.648 us; speedup vs baseline: 1.0538x; 1.0517x over previous
//
#include <hip/hip_runtime.h>
#include <cmath>

// ---------------------------------------------------------------------------
// T5 MHSA: x->(QKV proj, f16 MFMA GEMM) -> flash attn w/ T5 bias -> out proj
// All matmuls on MFMA. fp16 intermediates, fp32 accum.
// ---------------------------------------------------------------------------

typedef _Float16 f16x8 __attribute__((ext_vector_type(8)));
typedef _Float16 f16x4 __attribute__((ext_vector_type(4)));
typedef float    f32x4 __attribute__((ext_vector_type(4)));

#define NEG_INF (-__builtin_inff())
#define LOG2E 1.4426950408889634f

#if __has_builtin(__builtin_amdgcn_exp2f)
#define EXP2(x) __builtin_amdgcn_exp2f(x)
#else
#define EXP2(x) exp2f(x)
#endif

__device__ __forceinline__ void gl_lds16(const void* g, void* l) {
  __builtin_amdgcn_global_load_lds(
      (__attribute__((address_space(1))) void*)g,
      (__attribute__((address_space(3))) void*)l,
      16, 0, 0);
}

__device__ __forceinline__ f32x4 mfma32(f16x8 a, f16x8 b, f32x4 c) {
  return __builtin_amdgcn_mfma_f32_16x16x32_f16(a, b, c, 0, 0, 0);
}
__device__ __forceinline__ f32x4 mfma16(f16x4 a, f16x4 b, f32x4 c) {
  return __builtin_amdgcn_mfma_f32_16x16x16f16(a, b, c, 0, 0, 0);
}

typedef __attribute__((address_space(3))) _Float16* lds_f16p;

// -------------------------------- convert ---------------------------------
__global__ void cvt_kernel(const float* __restrict__ in,
                           _Float16* __restrict__ out, int n4) {
  int i = blockIdx.x * blockDim.x + threadIdx.x;
  if (i >= n4) return;
  float4 v = reinterpret_cast<const float4*>(in)[i];
  f16x4 o;
  o[0] = (_Float16)v.x; o[1] = (_Float16)v.y;
  o[2] = (_Float16)v.z; o[3] = (_Float16)v.w;
  reinterpret_cast<f16x4*>(out)[i] = o;
}

// --------------------------------- GEMM -----------------------------------
// C = A(MxK) * Bm(NxK)^T.  128x128 tile, BK=32, 4 waves (2x2 of 64x64).
// K-loop is fully waitcnt-opaque to the compiler: staging via
// global_load_lds, fragment loads via inline-asm ds_read_b128, ONLY counted
// asm vmcnt waits (never 0 in-loop) + raw s_barrier. This keeps the next
// tile's 4 loads in flight across the barrier (T3+T4).
#define GEMM_VM4 asm volatile("s_waitcnt vmcnt(4)" ::: "memory")
#define GEMM_VM0 asm volatile("s_waitcnt vmcnt(0)" ::: "memory")
#define GEMM_BAR __builtin_amdgcn_s_barrier()
#define DSR(d, a, o) \
  asm volatile("ds_read_b128 %0, %1 offset:" o : "=v"(d) : "v"(a))

#define GEMM_STAGE(buf, kk)                         \
  do {                                              \
    gl_lds16(pA0 + (kk), &lds_a[buf][wofs]);        \
    gl_lds16(pA1 + (kk), &lds_a[buf][2048 + wofs]); \
    gl_lds16(pB0 + (kk), &lds_b[buf][wofs]);        \
    gl_lds16(pB1 + (kk), &lds_b[buf][2048 + wofs]); \
  } while (0)

#define GEMM_COMPUTE(aB, bB)                                     \
  do {                                                           \
    f16x8 af[4], bf[4];                                          \
    DSR(af[0], aB, "0");                                         \
    DSR(af[1], aB, "1024");                                      \
    DSR(af[2], aB, "2048");                                      \
    DSR(af[3], aB, "3072");                                      \
    DSR(bf[0], bB, "0");                                         \
    DSR(bf[1], bB, "1024");                                      \
    DSR(bf[2], bB, "2048");                                      \
    DSR(bf[3], bB, "3072");                                      \
    asm volatile("s_waitcnt lgkmcnt(0)" ::: "memory");           \
    __builtin_amdgcn_sched_barrier(0);                           \
    __builtin_amdgcn_s_setprio(1);                               \
    _Pragma("unroll") for (int mi = 0; mi < 4; ++mi)             \
        _Pragma("unroll") for (int ni = 0; ni < 4; ++ni)         \
            acc[mi][ni] = mfma32(af[mi], bf[ni], acc[mi][ni]);   \
    __builtin_amdgcn_s_setprio(0);                               \
  } while (0)

template <int MODE>
__global__ __launch_bounds__(256, 3) void gemm_kernel(
    const _Float16* __restrict__ A, const _Float16* __restrict__ Bm,
    int M, int N, int K,
    const float* __restrict__ bias_q, const float* __restrict__ bias_v,
    _Float16* __restrict__ qkbuf, _Float16* __restrict__ vtbuf,
    const float* __restrict__ bias_o, float* __restrict__ outf) {
  __shared__ __align__(16) _Float16 lds_a[2][128 * 32];
  __shared__ __align__(16) _Float16 lds_b[2][128 * 32];
  const int t = threadIdx.x;
  const int w = t >> 6;
  const int lane = t & 63;
  const int lq = lane & 15, lg = lane >> 4;
  const int wr = w >> 1, wc = w & 1;

  // XCD chunk swizzle (T1): consecutive swizzled blocks share the A-panel.
  const int ngx = gridDim.x;
  const int nwg = ngx * gridDim.y;
  const int f = blockIdx.x + blockIdx.y * ngx;
  const int swz = (f & 7) * (nwg >> 3) + (f >> 3);
  const int bx = swz % ngx, by = swz / ngx;
  const int m0 = by * 128, n0 = bx * 128;

  // staging: thread t -> row t>>2 of tile, 8-elem k-chunk t&3; LDS dest is
  // wave-uniform base (+HW lane*16B) -> linear [128][32] layout
  const _Float16* pA0 = A + (size_t)(m0 + (t >> 2)) * K + (t & 3) * 8;
  const _Float16* pA1 = pA0 + (size_t)64 * K;
  const _Float16* pB0 = Bm + (size_t)(n0 + (t >> 2)) * K + (t & 3) * 8;
  const _Float16* pB1 = pB0 + (size_t)64 * K;
  const int wofs = w * 512;  // wave w's 64 lanes x 8 f16

  // asm ds_read base addresses (LDS byte offsets, per-lane)
  const uint32_t aB0 = (uint32_t)(uintptr_t)(lds_f16p)&lds_a[0][0] +
                       (uint32_t)((wr * 64 + lq) * 64 + lg * 16);
  const uint32_t aB1 = aB0 + 8192;
  const uint32_t bB0 = (uint32_t)(uintptr_t)(lds_f16p)&lds_b[0][0] +
                       (uint32_t)((wc * 64 + lq) * 64 + lg * 16);
  const uint32_t bB1 = bB0 + 8192;

  f32x4 acc[4][4];
#pragma unroll
  for (int mi = 0; mi < 4; ++mi)
#pragma unroll
    for (int ni = 0; ni < 4; ++ni) acc[mi][ni] = (f32x4){0.f, 0.f, 0.f, 0.f};

  // pipeline: two K-steps per body, literal buffer indices
  GEMM_STAGE(0, 0);
  for (int kt = 0; kt < K - 64; kt += 64) {
    GEMM_STAGE(1, kt + 32);
    GEMM_VM4;  // tile kt landed (kt+32's 4 loads stay in flight)
    GEMM_BAR;
    GEMM_COMPUTE(aB0, bB0);
    GEMM_BAR;
    GEMM_STAGE(0, kt + 64);
    GEMM_VM4;
    GEMM_BAR;
    GEMM_COMPUTE(aB1, bB1);
    GEMM_BAR;
  }
  GEMM_STAGE(1, K - 32);
  GEMM_VM4;
  GEMM_BAR;
  GEMM_COMPUTE(aB0, bB0);
  GEMM_BAR;
  GEMM_VM0;
  GEMM_BAR;
  GEMM_COMPUTE(aB1, bB1);

  if (MODE == 0) {
    const bool isqk = (n0 < 2048);
#pragma unroll
    for (int mi = 0; mi < 4; ++mi)
#pragma unroll
      for (int ni = 0; ni < 4; ++ni)
#pragma unroll
        for (int r = 0; r < 4; ++r) {
          const int mg = m0 + wr * 64 + mi * 16 + lg * 4 + r;
          const int ng = n0 + wc * 64 + ni * 16 + lq;
          const int bb = mg >> 10, ii = mg & 1023;
          float val = acc[mi][ni][r];
          if (isqk) {
            val += bias_q[ng];
            const int hh = ng >> 7, cc = ng & 127;
            qkbuf[((size_t)((bb * 16 + hh) * 1024 + ii)) * 128 + cc] =
                (_Float16)val;
          } else {
            const int nn = ng - 2048;
            val += bias_v[nn];
            const int hh = nn >> 6, dv = nn & 63;
            vtbuf[((size_t)((bb * 16 + hh) * 64 + dv)) * 1024 + ii] =
                (_Float16)val;
          }
        }
  } else {
#pragma unroll
    for (int mi = 0; mi < 4; ++mi)
#pragma unroll
      for (int ni = 0; ni < 4; ++ni)
#pragma unroll
        for (int r = 0; r < 4; ++r) {
          const int mg = m0 + wr * 64 + mi * 16 + lg * 4 + r;
          const int ng = n0 + wc * 64 + ni * 16 + lq;
          outf[(size_t)mg * N + ng] = acc[mi][ni][r] + bias_o[ng];
        }
  }
}

// ------------------------------- attention --------------------------------
// Block = 4 waves, owns q-tile PAIR (tA=b4, tB=15-b4) of one (b,h): constant
// work per block, all waves share the same j-range -> barrier-synced LDS
// staging of K/V tiles (KVBLK=64), double-buffered, swizzled.
__device__ __forceinline__ void stage_kv(const _Float16* __restrict__ kb,
                                         const _Float16* __restrict__ vtb,
                                         int j0, _Float16* kl, _Float16* vl,
                                         int t) {
  const int r0 = t >> 3, c0 = t & 7;
  const int r1 = r0 + 32;
  const int kc0 = c0 ^ (r0 & 7), kc1 = c0 ^ (r1 & 7);
  gl_lds16(kb + (size_t)(j0 + r0) * 128 + kc0 * 8, kl + t * 8);
  gl_lds16(kb + (size_t)(j0 + r1) * 128 + kc1 * 8, kl + (t + 256) * 8);
  gl_lds16(vtb + (size_t)r0 * 1024 + j0 + kc0 * 8, vl + t * 8);
  gl_lds16(vtb + (size_t)r1 * 1024 + j0 + kc1 * 8, vl + (t + 256) * 8);
}

__device__ __forceinline__ void softmax16(f32x4 (&st)[4], f16x4 (&ph)[4],
                                          int qi, int j0, bool far,
                                          const float* __restrict__ tab,
                                          float t128, int lg4, float& m_run,
                                          float& l_part, f32x4 (&oacc)[4]) {
  float xs[16];
  float lmax = NEG_INF;
  if (far) {
#pragma unroll
    for (int js = 0; js < 4; ++js)
#pragma unroll
      for (int r = 0; r < 4; ++r) {
        const float xv = fmaf(st[js][r], 0.125f * LOG2E, t128);
        xs[js * 4 + r] = xv;
        lmax = fmaxf(lmax, xv);
      }
  } else {
#pragma unroll
    for (int js = 0; js < 4; ++js)
#pragma unroll
      for (int r = 0; r < 4; ++r) {
        const int jj = j0 + js * 16 + lg4 + r;
        const int dd = qi - jj;
        const int idx = dd < 0 ? 0 : (dd > 128 ? 128 : dd);
        const float xv =
            (dd < 0) ? NEG_INF : fmaf(st[js][r], 0.125f * LOG2E, tab[idx]);
        xs[js * 4 + r] = xv;
        lmax = fmaxf(lmax, xv);
      }
  }
  if (__any(lmax > m_run + 8.0f)) {
    float tmax = fmaxf(lmax, __shfl_xor(lmax, 16));
    tmax = fmaxf(tmax, __shfl_xor(tmax, 32));
    const float m_new = fmaxf(m_run, tmax);
    const float sf = EXP2(m_run - m_new);
    m_run = m_new;
    l_part *= sf;
    f32x4 sfv;
#pragma unroll
    for (int r = 0; r < 4; ++r) sfv[r] = __shfl(sf, lg4 + r);
#pragma unroll
    for (int db = 0; db < 4; ++db) oacc[db] *= sfv;
  }
  float ls = 0.f;
#pragma unroll
  for (int js = 0; js < 4; ++js)
#pragma unroll
    for (int r = 0; r < 4; ++r) {
      const float p = EXP2(xs[js * 4 + r] - m_run);
      ls += p;
      ph[js][r] = (_Float16)p;
    }
  l_part += ls;
}

__global__ __launch_bounds__(256, 4) void attn_kernel(
    const _Float16* __restrict__ qk,  // [B*H][1024][128] (q | k)
    const _Float16* __restrict__ vt,  // [B*H][64][1024]  (V^T)
    const float* __restrict__ bias,   // [32][16]
    _Float16* __restrict__ ao) {      // [B][1024][H*64]
  __shared__ __align__(16) _Float16 kls[2][64 * 64];
  __shared__ __align__(16) _Float16 vls[2][64 * 64];
  __shared__ float tab[132];
  const int t = threadIdx.x;
  const int bid = blockIdx.x;
  const int bh = (bid & 7) * 16 + (bid >> 6);
  const int b4 = (bid >> 3) & 7;
  const int h = bh & 15, b = bh >> 4;
  if (t < 129) {
    const int bucket =
        (t <= 16) ? t : 16 + (int)(log((double)(t - 15)) * 15.0 / log(113.0));
    tab[t] = bias[bucket * 16 + h] * LOG2E;
  }

  const int w = t >> 6, lane = t & 63;
  const int lq = lane & 15, lg = lane >> 4;
  const int lg4 = lg * 4, lg8 = lg * 8;
  const int tA = b4, tB = 15 - b4;
  const int q0A = tA * 64 + w * 16, q0B = tB * 64 + w * 16;
  const int qA = q0A + lq, qB = q0B + lq;
  const _Float16* qkb = qk + (size_t)bh * 1024 * 128;
  const _Float16* kb = qkb + 64;
  const _Float16* vtb = vt + (size_t)bh * 64 * 1024;

  const f16x8 qfA0 = *(const f16x8*)&qkb[qA * 128 + lg8];
  const f16x8 qfA1 = *(const f16x8*)&qkb[qA * 128 + 32 + lg8];
  const f16x8 qfB0 = *(const f16x8*)&qkb[qB * 128 + lg8];
  const f16x8 qfB1 = *(const f16x8*)&qkb[qB * 128 + 32 + lg8];

  f32x4 oA[4], oB[4];
#pragma unroll
  for (int db = 0; db < 4; ++db) {
    oA[db] = (f32x4){0.f, 0.f, 0.f, 0.f};
    oB[db] = (f32x4){0.f, 0.f, 0.f, 0.f};
  }
  float mA = NEG_INF, lAp = 0.f, mB = NEG_INF, lBp = 0.f;

  stage_kv(kb, vtb, 0, kls[0], vls[0], t);
  __syncthreads();
  const float t128 = tab[128];
  const int krsw = lq & 7;
  const int vsw = (lq & 7) << 1;
  int cur = 0;

  for (int jt = 0; jt <= tB; ++jt) {
    const int j0 = jt * 64;
    if (jt < tB) stage_kv(kb, vtb, j0 + 64, kls[cur ^ 1], vls[cur ^ 1], t);
    const bool aact = (jt <= tA);
    const _Float16* kbf = kls[cur];
    const _Float16* vbf = vls[cur];

    f32x4 stA[4], stB[4];
#pragma unroll
    for (int js = 0; js < 4; ++js) {
      const int rowb = (js * 16 + lq) * 64;
      const f16x8 kf0 = *(const f16x8*)&kbf[rowb + ((lg ^ krsw) << 3)];
      const f16x8 kf1 = *(const f16x8*)&kbf[rowb + (((lg + 4) ^ krsw) << 3)];
      if (aact) {
        stA[js] = mfma32(kf0, qfA0, (f32x4){0.f, 0.f, 0.f, 0.f});
        stA[js] = mfma32(kf1, qfA1, stA[js]);
      }
      stB[js] = mfma32(kf0, qfB0, (f32x4){0.f, 0.f, 0.f, 0.f});
      stB[js] = mfma32(kf1, qfB1, stB[js]);
    }

    f16x4 phA[4], phB[4];
    if (aact)
      softmax16(stA, phA, qA, j0, q0A - j0 >= 192, tab, t128, lg4, mA, lAp,
                oA);
    softmax16(stB, phB, qB, j0, q0B - j0 >= 192, tab, t128, lg4, mB, lBp, oB);

#pragma unroll
    for (int js = 0; js < 4; ++js)
#pragma unroll
      for (int db = 0; db < 4; ++db) {
        const f16x4 vf = *(const f16x4*)&vbf[(db * 16 + lq) * 64 +
                                             ((((js << 2) + lg) ^ vsw) << 2)];
        if (aact) oA[db] = mfma16(phA[js], vf, oA[db]);
        oB[db] = mfma16(phB[js], vf, oB[db]);
      }

    __syncthreads();
    cur ^= 1;
  }

  _Float16* aob = ao + ((size_t)b * 1024) * 1024 + h * 64;
  {
    float lt = lAp + __shfl_xor(lAp, 16);
    lt += __shfl_xor(lt, 32);
    f32x4 linv;
#pragma unroll
    for (int r = 0; r < 4; ++r) linv[r] = 1.0f / __shfl(lt, lg4 + r);
#pragma unroll
    for (int db = 0; db < 4; ++db)
#pragma unroll
      for (int r = 0; r < 4; ++r)
        aob[(size_t)(q0A + lg4 + r) * 1024 + db * 16 + lq] =
            (_Float16)(oA[db][r] * linv[r]);
  }
  {
    float lt = lBp + __shfl_xor(lBp, 16);
    lt += __shfl_xor(lt, 32);
    f32x4 linv;
#pragma unroll
    for (int r = 0; r < 4; ++r) linv[r] = 1.0f / __shfl(lt, lg4 + r);
#pragma unroll
    for (int db = 0; db < 4; ++db)
#pragma unroll
      for (int r = 0; r < 4; ++r)
        aob[(size_t)(q0B + lg4 + r) * 1024 + db * 16 + lq] =
            (_Float16)(oB[db][r] * linv[r]);
  }
}

// -------------------------------- launch ----------------------------------
extern "C" void kernel_launch(void* const* d_in, const int* in_sizes, int n_in,
                              void* d_out, int out_size, void* d_ws,
                              size_t ws_size, hipStream_t stream) {
  const float* x = (const float*)d_in[0];
  const float* qk_w = (const float*)d_in[1];
  const float* qk_b = (const float*)d_in[2];
  const float* v_w = (const float*)d_in[3];
  const float* v_b = (const float*)d_in[4];
  const float* out_w = (const float*)d_in[5];
  const float* out_b = (const float*)d_in[6];
  const float* bias = (const float*)d_in[7];
  float* out = (float*)d_out;

  // workspace (fp16 elems): xb 8M | wb 3M | owb 1M | qk 16M | vt 8M | ao 8M
  _Float16* xb = (_Float16*)d_ws;
  _Float16* wb = xb + (size_t)8388608;
  _Float16* owb = wb + (size_t)3145728;
  _Float16* qkbuf = owb + (size_t)1048576;
  _Float16* vtbuf = qkbuf + (size_t)16777216;
  _Float16* ao = vtbuf + (size_t)8388608;

  cvt_kernel<<<8192, 256, 0, stream>>>(x, xb, 2097152);
  cvt_kernel<<<2048, 256, 0, stream>>>(qk_w, wb, 524288);
  cvt_kernel<<<1024, 256, 0, stream>>>(v_w, wb + 2097152, 262144);
  cvt_kernel<<<1024, 256, 0, stream>>>(out_w, owb, 262144);

  // fused QKV projection: M=8192, N=3072 (2048 qk | 1024 v), K=1024
  gemm_kernel<0><<<dim3(24, 64), 256, 0, stream>>>(
      xb, wb, 8192, 3072, 1024, qk_b, v_b, qkbuf, vtbuf, nullptr, nullptr);

  // flash attention: 8 balanced blocks per (b,h)
  attn_kernel<<<1024, 256, 0, stream>>>(qkbuf, vtbuf, bias, ao);

  // output projection: M=8192, N=1024, K=1024 -> fp32 d_out
  gemm_kernel<1><<<dim3(8, 64), 256, 0, stream>>>(
      ao, owb, 8192, 1024, 1024, nullptr, nullptr, nullptr, nullptr, out_b, out);
}

// Round 9
// 184.248 us; speedup vs baseline: 1.0560x; 1.0022x over previous
//
#include <hip/hip_runtime.h>
#include <cmath>

// ---------------------------------------------------------------------------
// T5 MHSA: x->(QKV proj, f16 MFMA GEMM) -> flash attn w/ T5 bias -> out proj
// All matmuls on MFMA. fp16 intermediates, fp32 accum.
// ---------------------------------------------------------------------------

typedef _Float16 f16x8 __attribute__((ext_vector_type(8)));
typedef _Float16 f16x4 __attribute__((ext_vector_type(4)));
typedef float    f32x4 __attribute__((ext_vector_type(4)));

#define NEG_INF (-__builtin_inff())
#define LOG2E 1.4426950408889634f

#if __has_builtin(__builtin_amdgcn_exp2f)
#define EXP2(x) __builtin_amdgcn_exp2f(x)
#else
#define EXP2(x) exp2f(x)
#endif

__device__ __forceinline__ void gl_lds16(const void* g, void* l) {
  __builtin_amdgcn_global_load_lds(
      (__attribute__((address_space(1))) void*)g,
      (__attribute__((address_space(3))) void*)l,
      16, 0, 0);
}

__device__ __forceinline__ f32x4 mfma32(f16x8 a, f16x8 b, f32x4 c) {
  return __builtin_amdgcn_mfma_f32_16x16x32_f16(a, b, c, 0, 0, 0);
}
__device__ __forceinline__ f32x4 mfma16(f16x4 a, f16x4 b, f32x4 c) {
  return __builtin_amdgcn_mfma_f32_16x16x16f16(a, b, c, 0, 0, 0);
}

typedef __attribute__((address_space(3))) _Float16* lds_f16p;

// -------------------------------- convert ---------------------------------
__global__ void cvt_kernel(const float* __restrict__ in,
                           _Float16* __restrict__ out, int n4) {
  int i = blockIdx.x * blockDim.x + threadIdx.x;
  if (i >= n4) return;
  float4 v = reinterpret_cast<const float4*>(in)[i];
  f16x4 o;
  o[0] = (_Float16)v.x; o[1] = (_Float16)v.y;
  o[2] = (_Float16)v.z; o[3] = (_Float16)v.w;
  reinterpret_cast<f16x4*>(out)[i] = o;
}

// --------------------------------- GEMM -----------------------------------
// C = A(MxK) * Bm(NxK)^T.  128x128 tile, BK=32, 4 waves (2x2 of 64x64).
// K-loop is waitcnt-opaque (asm ds_read + counted asm vmcnt + raw s_barrier)
// so the next tile's 4 global_load_lds stay in flight across the barrier.
// LDS chunk-XOR swizzle (both sides): staging source chunk c^((row>>1)&3),
// read slot lg^((lq>>1)&3) -> 16 rows hit 8 distinct 16B slots = 2-way(free).
// lgkmcnt ladder: 4 MFMAs overlap the last 4 ds_reads.
#define GEMM_VM4 asm volatile("s_waitcnt vmcnt(4)" ::: "memory")
#define GEMM_VM0 asm volatile("s_waitcnt vmcnt(0)" ::: "memory")
#define GEMM_BAR __builtin_amdgcn_s_barrier()
#define DSR(d, a, o) \
  asm volatile("ds_read_b128 %0, %1 offset:" o : "=v"(d) : "v"(a))

#define GEMM_STAGE(buf, kk)                         \
  do {                                              \
    gl_lds16(pA0 + (kk), &lds_a[buf][wofs]);        \
    gl_lds16(pA1 + (kk), &lds_a[buf][2048 + wofs]); \
    gl_lds16(pB0 + (kk), &lds_b[buf][wofs]);        \
    gl_lds16(pB1 + (kk), &lds_b[buf][2048 + wofs]); \
  } while (0)

#define GEMM_COMPUTE(aB, bB)                             \
  do {                                                   \
    f16x8 af0, af1, af2, af3, bf0, bf1, bf2, bf3;        \
    DSR(af0, aB, "0");                                   \
    DSR(bf0, bB, "0");                                   \
    DSR(af1, aB, "1024");                                \
    DSR(bf1, bB, "1024");                                \
    DSR(af2, aB, "2048");                                \
    DSR(bf2, bB, "2048");                                \
    DSR(af3, aB, "3072");                                \
    DSR(bf3, bB, "3072");                                \
    asm volatile("s_waitcnt lgkmcnt(4)" ::: "memory");   \
    __builtin_amdgcn_sched_barrier(0);                   \
    __builtin_amdgcn_s_setprio(1);                       \
    acc[0][0] = mfma32(af0, bf0, acc[0][0]);             \
    acc[0][1] = mfma32(af0, bf1, acc[0][1]);             \
    acc[1][0] = mfma32(af1, bf0, acc[1][0]);             \
    acc[1][1] = mfma32(af1, bf1, acc[1][1]);             \
    asm volatile("s_waitcnt lgkmcnt(0)" ::: "memory");   \
    __builtin_amdgcn_sched_barrier(0);                   \
    acc[0][2] = mfma32(af0, bf2, acc[0][2]);             \
    acc[0][3] = mfma32(af0, bf3, acc[0][3]);             \
    acc[1][2] = mfma32(af1, bf2, acc[1][2]);             \
    acc[1][3] = mfma32(af1, bf3, acc[1][3]);             \
    acc[2][0] = mfma32(af2, bf0, acc[2][0]);             \
    acc[2][1] = mfma32(af2, bf1, acc[2][1]);             \
    acc[2][2] = mfma32(af2, bf2, acc[2][2]);             \
    acc[2][3] = mfma32(af2, bf3, acc[2][3]);             \
    acc[3][0] = mfma32(af3, bf0, acc[3][0]);             \
    acc[3][1] = mfma32(af3, bf1, acc[3][1]);             \
    acc[3][2] = mfma32(af3, bf2, acc[3][2]);             \
    acc[3][3] = mfma32(af3, bf3, acc[3][3]);             \
    __builtin_amdgcn_s_setprio(0);                       \
  } while (0)

template <int MODE>
__global__ __launch_bounds__(256, 3) void gemm_kernel(
    const _Float16* __restrict__ A, const _Float16* __restrict__ Bm,
    int M, int N, int K,
    const float* __restrict__ bias_q, const float* __restrict__ bias_v,
    _Float16* __restrict__ qkbuf, _Float16* __restrict__ vtbuf,
    const float* __restrict__ bias_o, float* __restrict__ outf) {
  __shared__ __align__(16) _Float16 lds_a[2][128 * 32];
  __shared__ __align__(16) _Float16 lds_b[2][128 * 32];
  const int t = threadIdx.x;
  const int w = t >> 6;
  const int lane = t & 63;
  const int lq = lane & 15, lg = lane >> 4;
  const int wr = w >> 1, wc = w & 1;
  const int m0 = blockIdx.y * 128, n0 = blockIdx.x * 128;

  // staging: thread t -> row t>>2, SOURCE chunk (t&3)^((t>>3)&3) (inverse of
  // the read-side slot swizzle); LDS dest linear (wave base + lane*16B)
  const int stc = ((t & 3) ^ ((t >> 3) & 3)) * 8;
  const _Float16* pA0 = A + (size_t)(m0 + (t >> 2)) * K + stc;
  const _Float16* pA1 = pA0 + (size_t)64 * K;
  const _Float16* pB0 = Bm + (size_t)(n0 + (t >> 2)) * K + stc;
  const _Float16* pB1 = pB0 + (size_t)64 * K;
  const int wofs = w * 512;  // wave w's 64 lanes x 8 f16

  // asm ds_read base addresses (LDS byte offsets, per-lane, swizzled slot)
  const int xsw = (lq >> 1) & 3;
  const uint32_t aB0 = (uint32_t)(uintptr_t)(lds_f16p)&lds_a[0][0] +
                       (uint32_t)((wr * 64 + lq) * 64 + ((lg ^ xsw) << 4));
  const uint32_t aB1 = aB0 + 8192;
  const uint32_t bB0 = (uint32_t)(uintptr_t)(lds_f16p)&lds_b[0][0] +
                       (uint32_t)((wc * 64 + lq) * 64 + ((lg ^ xsw) << 4));
  const uint32_t bB1 = bB0 + 8192;

  f32x4 acc[4][4];
#pragma unroll
  for (int mi = 0; mi < 4; ++mi)
#pragma unroll
    for (int ni = 0; ni < 4; ++ni) acc[mi][ni] = (f32x4){0.f, 0.f, 0.f, 0.f};

  // pipeline: two K-steps per body, literal buffer indices
  GEMM_STAGE(0, 0);
  for (int kt = 0; kt < K - 64; kt += 64) {
    GEMM_STAGE(1, kt + 32);
    GEMM_VM4;  // tile kt landed (kt+32's 4 loads stay in flight)
    GEMM_BAR;
    GEMM_COMPUTE(aB0, bB0);
    GEMM_BAR;
    GEMM_STAGE(0, kt + 64);
    GEMM_VM4;
    GEMM_BAR;
    GEMM_COMPUTE(aB1, bB1);
    GEMM_BAR;
  }
  GEMM_STAGE(1, K - 32);
  GEMM_VM4;
  GEMM_BAR;
  GEMM_COMPUTE(aB0, bB0);
  GEMM_BAR;
  GEMM_VM0;
  GEMM_BAR;
  GEMM_COMPUTE(aB1, bB1);

  if (MODE == 0) {
    const bool isqk = (n0 < 2048);
#pragma unroll
    for (int mi = 0; mi < 4; ++mi)
#pragma unroll
      for (int ni = 0; ni < 4; ++ni)
#pragma unroll
        for (int r = 0; r < 4; ++r) {
          const int mg = m0 + wr * 64 + mi * 16 + lg * 4 + r;
          const int ng = n0 + wc * 64 + ni * 16 + lq;
          const int bb = mg >> 10, ii = mg & 1023;
          float val = acc[mi][ni][r];
          if (isqk) {
            val += bias_q[ng];
            const int hh = ng >> 7, cc = ng & 127;
            qkbuf[((size_t)((bb * 16 + hh) * 1024 + ii)) * 128 + cc] =
                (_Float16)val;
          } else {
            const int nn = ng - 2048;
            val += bias_v[nn];
            const int hh = nn >> 6, dv = nn & 63;
            vtbuf[((size_t)((bb * 16 + hh) * 64 + dv)) * 1024 + ii] =
                (_Float16)val;
          }
        }
  } else {
#pragma unroll
    for (int mi = 0; mi < 4; ++mi)
#pragma unroll
      for (int ni = 0; ni < 4; ++ni)
#pragma unroll
        for (int r = 0; r < 4; ++r) {
          const int mg = m0 + wr * 64 + mi * 16 + lg * 4 + r;
          const int ng = n0 + wc * 64 + ni * 16 + lq;
          outf[(size_t)mg * N + ng] = acc[mi][ni][r] + bias_o[ng];
        }
  }
}

// ------------------------------- attention --------------------------------
// Block = 4 waves, owns q-tile PAIR (tA=b4, tB=15-b4) of one (b,h): constant
// work per block, all waves share the same j-range -> barrier-synced LDS
// staging of K/V tiles (KVBLK=64), double-buffered, swizzled.
__device__ __forceinline__ void stage_kv(const _Float16* __restrict__ kb,
                                         const _Float16* __restrict__ vtb,
                                         int j0, _Float16* kl, _Float16* vl,
                                         int t) {
  const int r0 = t >> 3, c0 = t & 7;
  const int r1 = r0 + 32;
  const int kc0 = c0 ^ (r0 & 7), kc1 = c0 ^ (r1 & 7);
  gl_lds16(kb + (size_t)(j0 + r0) * 128 + kc0 * 8, kl + t * 8);
  gl_lds16(kb + (size_t)(j0 + r1) * 128 + kc1 * 8, kl + (t + 256) * 8);
  gl_lds16(vtb + (size_t)r0 * 1024 + j0 + kc0 * 8, vl + t * 8);
  gl_lds16(vtb + (size_t)r1 * 1024 + j0 + kc1 * 8, vl + (t + 256) * 8);
}

__device__ __forceinline__ void softmax16(f32x4 (&st)[4], f16x4 (&ph)[4],
                                          int qi, int j0, bool far,
                                          const float* __restrict__ tab,
                                          float t128, int lg4, float& m_run,
                                          float& l_part, f32x4 (&oacc)[4]) {
  float xs[16];
  float lmax = NEG_INF;
  if (far) {
#pragma unroll
    for (int js = 0; js < 4; ++js)
#pragma unroll
      for (int r = 0; r < 4; ++r) {
        const float xv = fmaf(st[js][r], 0.125f * LOG2E, t128);
        xs[js * 4 + r] = xv;
        lmax = fmaxf(lmax, xv);
      }
  } else {
#pragma unroll
    for (int js = 0; js < 4; ++js)
#pragma unroll
      for (int r = 0; r < 4; ++r) {
        const int jj = j0 + js * 16 + lg4 + r;
        const int dd = qi - jj;
        const int idx = dd < 0 ? 0 : (dd > 128 ? 128 : dd);
        const float xv =
            (dd < 0) ? NEG_INF : fmaf(st[js][r], 0.125f * LOG2E, tab[idx]);
        xs[js * 4 + r] = xv;
        lmax = fmaxf(lmax, xv);
      }
  }
  if (__any(lmax > m_run + 8.0f)) {
    float tmax = fmaxf(lmax, __shfl_xor(lmax, 16));
    tmax = fmaxf(tmax, __shfl_xor(tmax, 32));
    const float m_new = fmaxf(m_run, tmax);
    const float sf = EXP2(m_run - m_new);
    m_run = m_new;
    l_part *= sf;
    f32x4 sfv;
#pragma unroll
    for (int r = 0; r < 4; ++r) sfv[r] = __shfl(sf, lg4 + r);
#pragma unroll
    for (int db = 0; db < 4; ++db) oacc[db] *= sfv;
  }
  float ls = 0.f;
#pragma unroll
  for (int js = 0; js < 4; ++js)
#pragma unroll
    for (int r = 0; r < 4; ++r) {
      const float p = EXP2(xs[js * 4 + r] - m_run);
      ls += p;
      ph[js][r] = (_Float16)p;
    }
  l_part += ls;
}

__global__ __launch_bounds__(256, 4) void attn_kernel(
    const _Float16* __restrict__ qk,  // [B*H][1024][128] (q | k)
    const _Float16* __restrict__ vt,  // [B*H][64][1024]  (V^T)
    const float* __restrict__ bias,   // [32][16]
    _Float16* __restrict__ ao) {      // [B][1024][H*64]
  __shared__ __align__(16) _Float16 kls[2][64 * 64];
  __shared__ __align__(16) _Float16 vls[2][64 * 64];
  __shared__ float tab[132];
  const int t = threadIdx.x;
  const int bid = blockIdx.x;
  const int bh = (bid & 7) * 16 + (bid >> 6);
  const int b4 = (bid >> 3) & 7;
  const int h = bh & 15, b = bh >> 4;
  if (t < 129) {
    const int bucket =
        (t <= 16) ? t : 16 + (int)(log((double)(t - 15)) * 15.0 / log(113.0));
    tab[t] = bias[bucket * 16 + h] * LOG2E;
  }

  const int w = t >> 6, lane = t & 63;
  const int lq = lane & 15, lg = lane >> 4;
  const int lg4 = lg * 4, lg8 = lg * 8;
  const int tA = b4, tB = 15 - b4;
  const int q0A = tA * 64 + w * 16, q0B = tB * 64 + w * 16;
  const int qA = q0A + lq, qB = q0B + lq;
  const _Float16* qkb = qk + (size_t)bh * 1024 * 128;
  const _Float16* kb = qkb + 64;
  const _Float16* vtb = vt + (size_t)bh * 64 * 1024;

  const f16x8 qfA0 = *(const f16x8*)&qkb[qA * 128 + lg8];
  const f16x8 qfA1 = *(const f16x8*)&qkb[qA * 128 + 32 + lg8];
  const f16x8 qfB0 = *(const f16x8*)&qkb[qB * 128 + lg8];
  const f16x8 qfB1 = *(const f16x8*)&qkb[qB * 128 + 32 + lg8];

  f32x4 oA[4], oB[4];
#pragma unroll
  for (int db = 0; db < 4; ++db) {
    oA[db] = (f32x4){0.f, 0.f, 0.f, 0.f};
    oB[db] = (f32x4){0.f, 0.f, 0.f, 0.f};
  }
  float mA = NEG_INF, lAp = 0.f, mB = NEG_INF, lBp = 0.f;

  stage_kv(kb, vtb, 0, kls[0], vls[0], t);
  __syncthreads();
  const float t128 = tab[128];
  const int krsw = lq & 7;
  const int vsw = (lq & 7) << 1;
  int cur = 0;

  for (int jt = 0; jt <= tB; ++jt) {
    const int j0 = jt * 64;
    if (jt < tB) stage_kv(kb, vtb, j0 + 64, kls[cur ^ 1], vls[cur ^ 1], t);
    const bool aact = (jt <= tA);
    const _Float16* kbf = kls[cur];
    const _Float16* vbf = vls[cur];

    f32x4 stA[4], stB[4];
#pragma unroll
    for (int js = 0; js < 4; ++js) {
      const int rowb = (js * 16 + lq) * 64;
      const f16x8 kf0 = *(const f16x8*)&kbf[rowb + ((lg ^ krsw) << 3)];
      const f16x8 kf1 = *(const f16x8*)&kbf[rowb + (((lg + 4) ^ krsw) << 3)];
      if (aact) {
        stA[js] = mfma32(kf0, qfA0, (f32x4){0.f, 0.f, 0.f, 0.f});
        stA[js] = mfma32(kf1, qfA1, stA[js]);
      }
      stB[js] = mfma32(kf0, qfB0, (f32x4){0.f, 0.f, 0.f, 0.f});
      stB[js] = mfma32(kf1, qfB1, stB[js]);
    }

    f16x4 phA[4], phB[4];
    if (aact)
      softmax16(stA, phA, qA, j0, q0A - j0 >= 192, tab, t128, lg4, mA, lAp,
                oA);
    softmax16(stB, phB, qB, j0, q0B - j0 >= 192, tab, t128, lg4, mB, lBp, oB);

#pragma unroll
    for (int js = 0; js < 4; ++js)
#pragma unroll
      for (int db = 0; db < 4; ++db) {
        const f16x4 vf = *(const f16x4*)&vbf[(db * 16 + lq) * 64 +
                                             ((((js << 2) + lg) ^ vsw) << 2)];
        if (aact) oA[db] = mfma16(phA[js], vf, oA[db]);
        oB[db] = mfma16(phB[js], vf, oB[db]);
      }

    __syncthreads();
    cur ^= 1;
  }

  _Float16* aob = ao + ((size_t)b * 1024) * 1024 + h * 64;
  {
    float lt = lAp + __shfl_xor(lAp, 16);
    lt += __shfl_xor(lt, 32);
    f32x4 linv;
#pragma unroll
    for (int r = 0; r < 4; ++r) linv[r] = 1.0f / __shfl(lt, lg4 + r);
#pragma unroll
    for (int db = 0; db < 4; ++db)
#pragma unroll
      for (int r = 0; r < 4; ++r)
        aob[(size_t)(q0A + lg4 + r) * 1024 + db * 16 + lq] =
            (_Float16)(oA[db][r] * linv[r]);
  }
  {
    float lt = lBp + __shfl_xor(lBp, 16);
    lt += __shfl_xor(lt, 32);
    f32x4 linv;
#pragma unroll
    for (int r = 0; r < 4; ++r) linv[r] = 1.0f / __shfl(lt, lg4 + r);
#pragma unroll
    for (int db = 0; db < 4; ++db)
#pragma unroll
      for (int r = 0; r < 4; ++r)
        aob[(size_t)(q0B + lg4 + r) * 1024 + db * 16 + lq] =
            (_Float16)(oB[db][r] * linv[r]);
  }
}

// -------------------------------- launch ----------------------------------
extern "C" void kernel_launch(void* const* d_in, const int* in_sizes, int n_in,
                              void* d_out, int out_size, void* d_ws,
                              size_t ws_size, hipStream_t stream) {
  const float* x = (const float*)d_in[0];
  const float* qk_w = (const float*)d_in[1];
  const float* qk_b = (const float*)d_in[2];
  const float* v_w = (const float*)d_in[3];
  const float* v_b = (const float*)d_in[4];
  const float* out_w = (const float*)d_in[5];
  const float* out_b = (const float*)d_in[6];
  const float* bias = (const float*)d_in[7];
  float* out = (float*)d_out;

  // workspace (fp16 elems): xb 8M | wb 3M | owb 1M | qk 16M | vt 8M | ao 8M
  _Float16* xb = (_Float16*)d_ws;
  _Float16* wb = xb + (size_t)8388608;
  _Float16* owb = wb + (size_t)3145728;
  _Float16* qkbuf = owb + (size_t)1048576;
  _Float16* vtbuf = qkbuf + (size_t)16777216;
  _Float16* ao = vtbuf + (size_t)8388608;

  cvt_kernel<<<8192, 256, 0, stream>>>(x, xb, 2097152);
  cvt_kernel<<<2048, 256, 0, stream>>>(qk_w, wb, 524288);
  cvt_kernel<<<1024, 256, 0, stream>>>(v_w, wb + 2097152, 262144);
  cvt_kernel<<<1024, 256, 0, stream>>>(out_w, owb, 262144);

  // fused QKV projection: M=8192, N=3072 (2048 qk | 1024 v), K=1024
  gemm_kernel<0><<<dim3(24, 64), 256, 0, stream>>>(
      xb, wb, 8192, 3072, 1024, qk_b, v_b, qkbuf, vtbuf, nullptr, nullptr);

  // flash attention: 8 balanced blocks per (b,h)
  attn_kernel<<<1024, 256, 0, stream>>>(qkbuf, vtbuf, bias, ao);

  // output projection: M=8192, N=1024, K=1024 -> fp32 d_out
  gemm_kernel<1><<<dim3(8, 64), 256, 0, stream>>>(
      ao, owb, 8192, 1024, 1024, nullptr, nullptr, nullptr, nullptr, out_b, out);
}